// Round 1
// baseline (7797.039 us; speedup 1.0000x reference)
//
#include <hip/hip_runtime.h>

#define NE 800000
#define NN 100000
#define D 64
#define DIN 153      // 2*64 + 4 + 16 + 4 + 1
#define HD 128
#define TE 32        // edges per block

// fast tanh: tanh(x) = (exp(2x)-1)/(exp(2x)+1), via v_exp_f32 (2^x) and v_rcp_f32
__device__ __forceinline__ float ftanh(float x) {
    float cx = fminf(fmaxf(x, -15.f), 15.f);
    float e = __builtin_amdgcn_exp2f(cx * 2.885390081777927f);  // exp(2*cx)
    return (e - 1.f) * __builtin_amdgcn_rcpf(e + 1.f);
}

// one hidden layer: in LDS [K][TE] -> out LDS [128][TE], 16 channels/thread
template<int K>
__device__ __forceinline__ void dense16(const float* __restrict__ sin,
                                        const float* __restrict__ W,
                                        const float* __restrict__ b,
                                        float* __restrict__ sout,
                                        int e2, int cs) {
    float acc[16];
#pragma unroll
    for (int j = 0; j < 16; ++j) acc[j] = 0.f;
    const float* Wc = W + cs * 16;          // row stride 128, 64B-aligned slice
    for (int k = 0; k < K; ++k) {
        float a = sin[k * TE + e2];
        const float4* wr = (const float4*)(Wc + (size_t)k * HD);
        float4 w0 = wr[0], w1 = wr[1], w2 = wr[2], w3 = wr[3];
        acc[0]  += a * w0.x; acc[1]  += a * w0.y; acc[2]  += a * w0.z; acc[3]  += a * w0.w;
        acc[4]  += a * w1.x; acc[5]  += a * w1.y; acc[6]  += a * w1.z; acc[7]  += a * w1.w;
        acc[8]  += a * w2.x; acc[9]  += a * w2.y; acc[10] += a * w2.z; acc[11] += a * w2.w;
        acc[12] += a * w3.x; acc[13] += a * w3.y; acc[14] += a * w3.z; acc[15] += a * w3.w;
    }
#pragma unroll
    for (int j = 0; j < 16; ++j) {
        float h = ftanh(acc[j] + b[cs * 16 + j]);
        sout[(cs * 16 + j) * TE + e2] = h;
    }
}

// final layer (128 -> 64) + tanh + atomic scatter, 8 channels/thread
__device__ __forceinline__ void dense8_scatter(const float* __restrict__ sin,
                                               const float* __restrict__ W,
                                               const float* __restrict__ b,
                                               float* __restrict__ out,
                                               int node, int e2, int cs) {
    float acc[8];
#pragma unroll
    for (int j = 0; j < 8; ++j) acc[j] = 0.f;
    const float* Wc = W + cs * 8;           // row stride 64, 32B-aligned slice
    for (int k = 0; k < HD; ++k) {
        float a = sin[k * TE + e2];
        const float4* wr = (const float4*)(Wc + (size_t)k * D);
        float4 w0 = wr[0], w1 = wr[1];
        acc[0] += a * w0.x; acc[1] += a * w0.y; acc[2] += a * w0.z; acc[3] += a * w0.w;
        acc[4] += a * w1.x; acc[5] += a * w1.y; acc[6] += a * w1.z; acc[7] += a * w1.w;
    }
    float* op = out + (size_t)node * D + cs * 8;
#pragma unroll
    for (int j = 0; j < 8; ++j) {
        float d = ftanh(acc[j] + b[cs * 8 + j]);
        unsafeAtomicAdd(op + j, d);
    }
}

__global__ __launch_bounds__(256) void edge_mlp_kernel(
    const int* __restrict__ addr_from, const int* __restrict__ addr_to,
    const float* __restrict__ h_local, const float* __restrict__ h_global,
    const float* __restrict__ x_local, const float* __restrict__ x_global,
    const float* __restrict__ tsc,
    const float* __restrict__ fW0, const float* __restrict__ fb0,
    const float* __restrict__ fW1, const float* __restrict__ fb1,
    const float* __restrict__ fW2, const float* __restrict__ fb2,
    const float* __restrict__ tW0, const float* __restrict__ tb0,
    const float* __restrict__ tW1, const float* __restrict__ tb1,
    const float* __restrict__ tW2, const float* __restrict__ tb2,
    float* __restrict__ out)
{
    __shared__ float s_inp[DIN * TE];   // [k][e]; reused as h1 [128][32] later
    __shared__ float s_h0f[HD * TE];    // [k][e]
    __shared__ float s_h0t[HD * TE];
    __shared__ int s_af[TE], s_at[TE];

    const int tid = threadIdx.x;
    const int eb = blockIdx.x * TE;

    // ---- stage input tile, transposed [k][e] ----
    {
        int eg = tid >> 3;                 // edge in tile 0..31
        int ks = tid & 7;                  // 8 threads per edge
        int e = eb + eg;
        int af = addr_from[e];
        int at = addr_to[e];
        if (ks == 0) { s_af[eg] = af; s_at[eg] = at; }

        const float4* hf = (const float4*)(h_local + (size_t)af * D);
        float4 u0 = hf[ks * 2], u1 = hf[ks * 2 + 1];
        int k0 = ks * 8;
        s_inp[(k0 + 0) * TE + eg] = u0.x; s_inp[(k0 + 1) * TE + eg] = u0.y;
        s_inp[(k0 + 2) * TE + eg] = u0.z; s_inp[(k0 + 3) * TE + eg] = u0.w;
        s_inp[(k0 + 4) * TE + eg] = u1.x; s_inp[(k0 + 5) * TE + eg] = u1.y;
        s_inp[(k0 + 6) * TE + eg] = u1.z; s_inp[(k0 + 7) * TE + eg] = u1.w;

        const float4* ht = (const float4*)(h_local + (size_t)at * D);
        float4 v0 = ht[ks * 2], v1 = ht[ks * 2 + 1];
        int k1 = 64 + ks * 8;
        s_inp[(k1 + 0) * TE + eg] = v0.x; s_inp[(k1 + 1) * TE + eg] = v0.y;
        s_inp[(k1 + 2) * TE + eg] = v0.z; s_inp[(k1 + 3) * TE + eg] = v0.w;
        s_inp[(k1 + 4) * TE + eg] = v1.x; s_inp[(k1 + 5) * TE + eg] = v1.y;
        s_inp[(k1 + 6) * TE + eg] = v1.z; s_inp[(k1 + 7) * TE + eg] = v1.w;

        // tail: k = 128..152 = [x_local(4), h_global(16), x_global(4), t(1)]
        for (int j = ks; j < 25; j += 8) {
            float v;
            if (j < 4)       v = x_local[(size_t)e * 4 + j];
            else if (j < 20) v = h_global[j - 4];
            else if (j < 24) v = x_global[j - 20];
            else             v = tsc[0];
            s_inp[(128 + j) * TE + eg] = v;
        }
    }
    __syncthreads();

    const int e2 = tid & 31;
    const int cs = tid >> 5;   // 0..7

    // layer 0 for both MLPs (both read s_inp)
    dense16<DIN>(s_inp, fW0, fb0, s_h0f, e2, cs);
    dense16<DIN>(s_inp, tW0, tb0, s_h0t, e2, cs);
    __syncthreads();

    // f-MLP: layer1 -> s_inp (alias), layer2 -> scatter
    dense16<HD>(s_h0f, fW1, fb1, s_inp, e2, cs);
    __syncthreads();
    dense8_scatter(s_inp, fW2, fb2, out, s_af[e2], e2, cs);
    __syncthreads();

    // t-MLP
    dense16<HD>(s_h0t, tW1, tb1, s_inp, e2, cs);
    __syncthreads();
    dense8_scatter(s_inp, tW2, tb2, out, s_at[e2], e2, cs);
}

__global__ __launch_bounds__(256) void tanh_kernel(float* __restrict__ out, int n4) {
    int i = blockIdx.x * blockDim.x + threadIdx.x;
    int stride = gridDim.x * blockDim.x;
    float4* p = (float4*)out;
    for (; i < n4; i += stride) {
        float4 v = p[i];
        v.x = ftanh(v.x); v.y = ftanh(v.y); v.z = ftanh(v.z); v.w = ftanh(v.w);
        p[i] = v;
    }
}

extern "C" void kernel_launch(void* const* d_in, const int* in_sizes, int n_in,
                              void* d_out, int out_size, void* d_ws, size_t ws_size,
                              hipStream_t stream) {
    const int*   addr_from = (const int*)d_in[0];
    const int*   addr_to   = (const int*)d_in[1];
    const float* h_local   = (const float*)d_in[2];
    const float* h_global  = (const float*)d_in[3];
    const float* x_local   = (const float*)d_in[4];
    const float* x_global  = (const float*)d_in[5];
    const float* tsc       = (const float*)d_in[6];
    const float* fW0 = (const float*)d_in[7];
    const float* fb0 = (const float*)d_in[8];
    const float* fW1 = (const float*)d_in[9];
    const float* fb1 = (const float*)d_in[10];
    const float* fW2 = (const float*)d_in[11];
    const float* fb2 = (const float*)d_in[12];
    const float* tW0 = (const float*)d_in[13];
    const float* tb0 = (const float*)d_in[14];
    const float* tW1 = (const float*)d_in[15];
    const float* tb1 = (const float*)d_in[16];
    const float* tW2 = (const float*)d_in[17];
    const float* tb2 = (const float*)d_in[18];
    float* out = (float*)d_out;

    hipMemsetAsync(d_out, 0, (size_t)NN * D * sizeof(float), stream);

    edge_mlp_kernel<<<NE / TE, 256, 0, stream>>>(
        addr_from, addr_to, h_local, h_global, x_local, x_global, tsc,
        fW0, fb0, fW1, fb1, fW2, fb2, tW0, tb0, tW1, tb1, tW2, tb2, out);

    tanh_kernel<<<2048, 256, 0, stream>>>(out, NN * D / 4);
}

// Round 4
// 1437.598 us; speedup vs baseline: 5.4237x; 5.4237x over previous
//
#include <hip/hip_runtime.h>

typedef unsigned int uint;
typedef unsigned short ushort;
typedef short bf16x8 __attribute__((ext_vector_type(8)));
typedef float f32x4 __attribute__((ext_vector_type(4)));
typedef uint u32x4 __attribute__((ext_vector_type(4)));

#define NE 800000
#define NN 100000
#define TE 64
#define SA 164   // f32 row stride of sA (656 B = 41*16, 16B-aligned)
#define SH 132   // f32 row stride of sH (528 B = 33*16, 16B-aligned)

__device__ __forceinline__ float ftanh(float x) {
    float cx = fminf(fmaxf(x, -15.f), 15.f);
    float e = __builtin_amdgcn_exp2f(cx * 2.885390081777927f);  // exp(2*cx)
    return (e - 1.f) * __builtin_amdgcn_rcpf(e + 1.f);
}

// split fp32 into bf16 hi (truncate) + bf16 lo (truncated residual)
__device__ __forceinline__ void bfsplit(float x, ushort& hi, ushort& lo) {
    uint xb = __builtin_bit_cast(uint, x);
    hi = (ushort)(xb >> 16);
    float hif = __builtin_bit_cast(float, xb & 0xFFFF0000u);
    float res = x - hif;
    lo = (ushort)(__builtin_bit_cast(uint, res) >> 16);
}

// 8 f32 -> bf16x8 hi plane + bf16x8 lo plane
__device__ __forceinline__ void split8(const float* v, bf16x8& fh, bf16x8& fl) {
    u32x4 H, L;
#pragma unroll
    for (int i = 0; i < 4; ++i) {
        ushort h0, l0, h1, l1;
        bfsplit(v[2*i],   h0, l0);
        bfsplit(v[2*i+1], h1, l1);
        H[i] = (uint)h0 | ((uint)h1 << 16);
        L[i] = (uint)l0 | ((uint)l1 << 16);
    }
    fh = __builtin_bit_cast(bf16x8, H);
    fl = __builtin_bit_cast(bf16x8, L);
}

// One dense layer on the 64-edge tile via 16x16x32 bf16 MFMA.
// A: f32 in LDS [edge][k]. W: f32 in GLOBAL, original [k][N] row-major, gathered
// per fragment (16-lane group reads 16 consecutive floats of one W row).
// 8 waves: mt = wave>>1 (16 edge rows), ntb = (wave&1)*NTW (col-tile half).
template<int KC, int NT, int KACT, bool SCATTER>
__device__ __forceinline__ void layer(
    const float* __restrict__ sA, int astr,
    const float* __restrict__ gW, const float* __restrict__ bias,
    float* __restrict__ sO,
    float* __restrict__ out, const int* __restrict__ s_nodes, int tid)
{
    constexpr int NTW = NT / 2;
    constexpr int N = NT * 16;
    const int lane = tid & 63;
    const int wave = tid >> 6;
    const int mt   = wave >> 1;
    const int ntb  = (wave & 1) * NTW;
    const int arow = mt * 16 + (lane & 15);
    const int kg   = (lane >> 4) * 8;
    const int nn   = lane & 15;

    f32x4 aHH[NTW], aLH[NTW], aHL[NTW];
#pragma unroll
    for (int i = 0; i < NTW; ++i)
#pragma unroll
        for (int r = 0; r < 4; ++r) { aHH[i][r] = 0.f; aLH[i][r] = 0.f; aHL[i][r] = 0.f; }

#pragma unroll
    for (int kc = 0; kc < KC; ++kc) {
        const float* ap = sA + arow * astr + kc * 32 + kg;
        float av[8];
        float4 a0 = *(const float4*)ap;
        float4 a1 = *(const float4*)(ap + 4);
        av[0]=a0.x; av[1]=a0.y; av[2]=a0.z; av[3]=a0.w;
        av[4]=a1.x; av[5]=a1.y; av[6]=a1.z; av[7]=a1.w;
        bf16x8 ah, al; split8(av, ah, al);
#pragma unroll
        for (int i = 0; i < NTW; ++i) {
            int n = (ntb + i) * 16 + nn;
            float wv[8];
#pragma unroll
            for (int j = 0; j < 8; ++j) {
                int k = kc * 32 + kg + j;
                float w = 0.f;
                if (KC * 32 <= KACT || k < KACT)   // compile-time elided when exact
                    w = gW[(size_t)k * N + n];
                wv[j] = w;
            }
            bf16x8 bh, bl; split8(wv, bh, bl);
            aHH[i] = __builtin_amdgcn_mfma_f32_16x16x32_bf16(ah, bh, aHH[i], 0, 0, 0);
            aLH[i] = __builtin_amdgcn_mfma_f32_16x16x32_bf16(al, bh, aLH[i], 0, 0, 0);
            aHL[i] = __builtin_amdgcn_mfma_f32_16x16x32_bf16(ah, bl, aHL[i], 0, 0, 0);
        }
    }

    if (!SCATTER) __syncthreads();   // all LDS reads done -> in-place output safe

#pragma unroll
    for (int i = 0; i < NTW; ++i) {
        int n = (ntb + i) * 16 + nn;
        float bv = bias[n];
#pragma unroll
        for (int r = 0; r < 4; ++r) {
            int m = mt * 16 + ((lane >> 4) << 2) + r;   // C/D: row=(lane>>4)*4+reg
            float h = ftanh(aHH[i][r] + aLH[i][r] + aHL[i][r] + bv);
            if (SCATTER) {
                unsafeAtomicAdd(out + (size_t)s_nodes[m] * 64 + n, h);
            } else {
                sO[m * SH + n] = h;
            }
        }
    }
}

__global__ __launch_bounds__(512) void edge_mlp(
    const int* __restrict__ af_, const int* __restrict__ at_,
    const float* __restrict__ h_local, const float* __restrict__ h_global,
    const float* __restrict__ x_local, const float* __restrict__ x_global,
    const float* __restrict__ tsc,
    const float* __restrict__ fW0, const float* __restrict__ fb0,
    const float* __restrict__ fW1, const float* __restrict__ fb1,
    const float* __restrict__ fW2, const float* __restrict__ fb2,
    const float* __restrict__ tW0, const float* __restrict__ tb0,
    const float* __restrict__ tW1, const float* __restrict__ tb1,
    const float* __restrict__ tW2, const float* __restrict__ tb2,
    float* __restrict__ out)
{
    __shared__ float sA[TE * SA];   // 41984 B, input tile [edge][k], k<160 (153 used)
    __shared__ float sH[TE * SH];   // 33792 B, hidden tile, reused in-place
    __shared__ int s_af[TE], s_at[TE];

    const int tid = threadIdx.x;
    const int e = tid >> 3, part = tid & 7;
    const int eg = blockIdx.x * TE + e;
    {
        int af = af_[eg], at = at_[eg];
        if (part == 0) { s_af[e] = af; s_at[e] = at; }
        int node = (part < 4) ? af : at;
        int k0 = ((part & 3) << 4) + ((part < 4) ? 0 : 64);
        const float4* hp = (const float4*)(h_local + (size_t)node * 64 + ((part & 3) << 4));
        float4* dst = (float4*)(sA + e * SA + k0);
        dst[0] = hp[0]; dst[1] = hp[1]; dst[2] = hp[2]; dst[3] = hp[3];
        if (part < 2) {
            int k0t = 128 + part * 16;
#pragma unroll
            for (int i = 0; i < 16; ++i) {
                int k = k0t + i;
                float x;
                if      (k < 132)  x = x_local[(size_t)eg * 4 + (k - 128)];
                else if (k < 148)  x = h_global[k - 132];
                else if (k < 152)  x = x_global[k - 148];
                else if (k == 152) x = tsc[0];
                else               x = 0.f;
                sA[e * SA + k] = x;
            }
        }
    }
    __syncthreads();
    // f MLP
    layer<5,8,153,false>(sA, SA, fW0, fb0, sH, nullptr, nullptr, tid);
    __syncthreads();
    layer<4,8,128,false>(sH, SH, fW1, fb1, sH, nullptr, nullptr, tid);
    __syncthreads();
    layer<4,4,128,true >(sH, SH, fW2, fb2, nullptr, out, s_af, tid);
    __syncthreads();
    // t MLP (sA still intact)
    layer<5,8,153,false>(sA, SA, tW0, tb0, sH, nullptr, nullptr, tid);
    __syncthreads();
    layer<4,8,128,false>(sH, SH, tW1, tb1, sH, nullptr, nullptr, tid);
    __syncthreads();
    layer<4,4,128,true >(sH, SH, tW2, tb2, nullptr, out, s_at, tid);
}

__global__ __launch_bounds__(256) void tanh_kernel(float* __restrict__ out, int n4) {
    int i = blockIdx.x * blockDim.x + threadIdx.x;
    int stride = gridDim.x * blockDim.x;
    float4* p = (float4*)out;
    for (; i < n4; i += stride) {
        float4 v = p[i];
        v.x = ftanh(v.x); v.y = ftanh(v.y); v.z = ftanh(v.z); v.w = ftanh(v.w);
        p[i] = v;
    }
}

extern "C" void kernel_launch(void* const* d_in, const int* in_sizes, int n_in,
                              void* d_out, int out_size, void* d_ws, size_t ws_size,
                              hipStream_t stream) {
    const int*   addr_from = (const int*)d_in[0];
    const int*   addr_to   = (const int*)d_in[1];
    const float* h_local   = (const float*)d_in[2];
    const float* h_global  = (const float*)d_in[3];
    const float* x_local   = (const float*)d_in[4];
    const float* x_global  = (const float*)d_in[5];
    const float* tsc       = (const float*)d_in[6];
    const float* fW0 = (const float*)d_in[7];
    const float* fb0 = (const float*)d_in[8];
    const float* fW1 = (const float*)d_in[9];
    const float* fb1 = (const float*)d_in[10];
    const float* fW2 = (const float*)d_in[11];
    const float* fb2 = (const float*)d_in[12];
    const float* tW0 = (const float*)d_in[13];
    const float* tb0 = (const float*)d_in[14];
    const float* tW1 = (const float*)d_in[15];
    const float* tb1 = (const float*)d_in[16];
    const float* tW2 = (const float*)d_in[17];
    const float* tb2 = (const float*)d_in[18];
    float* out = (float*)d_out;

    hipMemsetAsync(d_out, 0, (size_t)NN * 64 * sizeof(float), stream);
    edge_mlp<<<NE / TE, 512, 0, stream>>>(
        addr_from, addr_to, h_local, h_global, x_local, x_global, tsc,
        fW0, fb0, fW1, fb1, fW2, fb2, tW0, tb0, tW1, tb1, tW2, tb2, out);
    tanh_kernel<<<2048, 256, 0, stream>>>(out, NN * 64 / 4);
}

// Round 5
// 784.019 us; speedup vs baseline: 9.9450x; 1.8336x over previous
//
#include <hip/hip_runtime.h>

typedef unsigned int uint;
typedef unsigned short ushort;
typedef short bf16x8 __attribute__((ext_vector_type(8)));
typedef float f32x4 __attribute__((ext_vector_type(4)));
typedef uint u32x4 __attribute__((ext_vector_type(4)));

#define NE 800000
#define NN 100000
#define TE 64
#define ASTR 168   // ushort row stride of input planes (336 B)
#define HSTR 136   // ushort row stride of hidden planes (272 B)
#define SA 164     // f32 row stride (gather-fallback kernel)
#define SH 132

// packed-weight offsets (ushort elems) in d_ws. Layer sizes:
// L0: 5kc*2pl*8nt*512 = 40960, L1: 4*2*8*512 = 32768, L2: 4*2*4*512 = 16384
#define F0_OFF 0
#define F1_OFF 40960
#define F2_OFF 73728
#define T0_OFF 90112
#define T1_OFF 131072
#define T2_OFF 163840     // FIXED: T1 + L1 (was 147456 in R2/R3 -> overlap bug)
#define WPK_TOTAL 180224  // = T2 + 16384, exact
#define WPK_BYTES (WPK_TOTAL * 2)

__device__ __forceinline__ float ftanh(float x) {
    float cx = fminf(fmaxf(x, -15.f), 15.f);
    float e = __builtin_amdgcn_exp2f(cx * 2.885390081777927f);  // exp(2*cx)
    return (e - 1.f) * __builtin_amdgcn_rcpf(e + 1.f);
}

__device__ __forceinline__ void bfsplit(float x, ushort& hi, ushort& lo) {
    uint xb = __builtin_bit_cast(uint, x);
    hi = (ushort)(xb >> 16);
    float hif = __builtin_bit_cast(float, xb & 0xFFFF0000u);
    float res = x - hif;
    lo = (ushort)(__builtin_bit_cast(uint, res) >> 16);
}

__device__ __forceinline__ void split8(const float* v, bf16x8& fh, bf16x8& fl) {
    u32x4 H, L;
#pragma unroll
    for (int i = 0; i < 4; ++i) {
        ushort h0, l0, h1, l1;
        bfsplit(v[2*i],   h0, l0);
        bfsplit(v[2*i+1], h1, l1);
        H[i] = (uint)h0 | ((uint)h1 << 16);
        L[i] = (uint)l0 | ((uint)l1 << 16);
    }
    fh = __builtin_bit_cast(bf16x8, H);
    fl = __builtin_bit_cast(bf16x8, L);
}

// ---- weight pack: addr = base + ((kc*2+plane)*NT + nt)*512 + lane*8 + j ----
// value = W[k = kc*32 + (lane>>4)*8 + j][n = nt*16 + (lane&15)], zero-pad k>=Kact
__global__ __launch_bounds__(256) void pack_w(
    const float* __restrict__ fW0, const float* __restrict__ fW1, const float* __restrict__ fW2,
    const float* __restrict__ tW0, const float* __restrict__ tW1, const float* __restrict__ tW2,
    ushort* __restrict__ wpk)
{
    int idx = blockIdx.x * 256 + threadIdx.x;   // < WPK_TOTAL
    const float* src; int NT, Kact, base;
    if      (idx < F1_OFF) { src = fW0; NT = 8; Kact = 153; base = F0_OFF; }
    else if (idx < F2_OFF) { src = fW1; NT = 8; Kact = 128; base = F1_OFF; }
    else if (idx < T0_OFF) { src = fW2; NT = 4; Kact = 128; base = F2_OFF; }
    else if (idx < T1_OFF) { src = tW0; NT = 8; Kact = 153; base = T0_OFF; }
    else if (idx < T2_OFF) { src = tW1; NT = 8; Kact = 128; base = T1_OFF; }
    else                   { src = tW2; NT = 4; Kact = 128; base = T2_OFF; }
    int rel  = idx - base;
    int j    = rel & 7;
    int lane = (rel >> 3) & 63;
    int sub  = rel >> 9;
    int lnt  = (NT == 8) ? 3 : 2;
    int nt    = sub & (NT - 1);
    int plane = (sub >> lnt) & 1;
    int kc    = sub >> (lnt + 1);
    int k = kc * 32 + ((lane >> 4) << 3) + j;
    int n = nt * 16 + (lane & 15);
    int N = NT * 16;
    float w = (k < Kact) ? src[(size_t)k * N + n] : 0.f;
    ushort hi, lo; bfsplit(w, hi, lo);
    wpk[idx] = plane ? lo : hi;
}

// ================= packed-weight main kernel =================
// A in LDS hi/lo bf16 planes; W pre-split fragments in global (L2-resident).
template<int KC, int NT, bool INPLACE, bool SCATTER>
__device__ __forceinline__ void layer_p(
    const ushort* __restrict__ sAh, const ushort* __restrict__ sAl, int astr,
    const ushort* __restrict__ gW, const float* __restrict__ bias,
    ushort* __restrict__ sOh, ushort* __restrict__ sOl,
    float* __restrict__ out, const int* __restrict__ s_nodes, int tid)
{
    constexpr int NTW = NT / 2;
    const int lane = tid & 63;
    const int wave = tid >> 6;
    const int mt   = wave >> 1;
    const int ntb  = (wave & 1) * NTW;
    const int arow = mt * 16 + (lane & 15);
    const int kg   = (lane >> 4) * 8;
    const int nn   = lane & 15;
    const ushort* apH = sAh + arow * astr + kg;
    const ushort* apL = sAl + arow * astr + kg;

    f32x4 aHH[NTW], aLH[NTW], aHL[NTW];
#pragma unroll
    for (int i = 0; i < NTW; ++i)
#pragma unroll
        for (int r = 0; r < 4; ++r) { aHH[i][r] = 0.f; aLH[i][r] = 0.f; aHL[i][r] = 0.f; }

#pragma unroll
    for (int kc = 0; kc < KC; ++kc) {
        bf16x8 ah = *(const bf16x8*)(apH + kc * 32);
        bf16x8 al = *(const bf16x8*)(apL + kc * 32);
#pragma unroll
        for (int i = 0; i < NTW; ++i) {
            bf16x8 bh = *(const bf16x8*)(gW + ((size_t)(kc * 2 + 0) * NT + ntb + i) * 512 + lane * 8);
            bf16x8 bl = *(const bf16x8*)(gW + ((size_t)(kc * 2 + 1) * NT + ntb + i) * 512 + lane * 8);
            aHH[i] = __builtin_amdgcn_mfma_f32_16x16x32_bf16(ah, bh, aHH[i], 0, 0, 0);
            aLH[i] = __builtin_amdgcn_mfma_f32_16x16x32_bf16(al, bh, aLH[i], 0, 0, 0);
            aHL[i] = __builtin_amdgcn_mfma_f32_16x16x32_bf16(ah, bl, aHL[i], 0, 0, 0);
        }
    }

    if (INPLACE) __syncthreads();   // all reads of sO done before overwrite

#pragma unroll
    for (int i = 0; i < NTW; ++i) {
        int n = (ntb + i) * 16 + nn;
        float bv = bias[n];
#pragma unroll
        for (int r = 0; r < 4; ++r) {
            int m = mt * 16 + ((lane >> 4) << 2) + r;   // C/D: row=(lane>>4)*4+reg
            float h = ftanh(aHH[i][r] + aLH[i][r] + aHL[i][r] + bv);
            if (SCATTER) {
                unsafeAtomicAdd(out + (size_t)s_nodes[m] * 64 + n, h);
            } else {
                ushort hi, lo; bfsplit(h, hi, lo);
                sOh[m * HSTR + n] = hi;
                sOl[m * HSTR + n] = lo;
            }
        }
    }
}

__global__ __launch_bounds__(512, 4) void edge_mlp_packed(
    const int* __restrict__ af_, const int* __restrict__ at_,
    const float* __restrict__ h_local, const float* __restrict__ h_global,
    const float* __restrict__ x_local, const float* __restrict__ x_global,
    const float* __restrict__ tsc,
    const float* __restrict__ fb0, const float* __restrict__ fb1, const float* __restrict__ fb2,
    const float* __restrict__ tb0, const float* __restrict__ tb1, const float* __restrict__ tb2,
    const ushort* __restrict__ wpk, float* __restrict__ out)
{
    __shared__ ushort sAh[TE * ASTR], sAl[TE * ASTR];   // 21504 B each
    __shared__ ushort sHh[TE * HSTR], sHl[TE * HSTR];   // 17408 B each
    __shared__ int s_af[TE], s_at[TE];                  // total 78336 B

    const int tid = threadIdx.x;
    const int e = tid >> 3, part = tid & 7;
    const int eg = blockIdx.x * TE + e;
    {
        int af = af_[eg], at = at_[eg];
        if (part == 0) { s_af[e] = af; s_at[e] = at; }
        int node = (part < 4) ? af : at;
        int k0 = ((part & 3) << 4) + ((part < 4) ? 0 : 64);
        const float4* hp = (const float4*)(h_local + (size_t)node * 64 + ((part & 3) << 4));
        float4 q0 = hp[0], q1 = hp[1], q2 = hp[2], q3 = hp[3];
        float v[16] = {q0.x,q0.y,q0.z,q0.w, q1.x,q1.y,q1.z,q1.w,
                       q2.x,q2.y,q2.z,q2.w, q3.x,q3.y,q3.z,q3.w};
        uint* dh = (uint*)(sAh + e * ASTR + k0);
        uint* dl = (uint*)(sAl + e * ASTR + k0);
#pragma unroll
        for (int i = 0; i < 8; ++i) {
            ushort h0, l0, h1, l1;
            bfsplit(v[2*i], h0, l0); bfsplit(v[2*i+1], h1, l1);
            dh[i] = (uint)h0 | ((uint)h1 << 16);
            dl[i] = (uint)l0 | ((uint)l1 << 16);
        }
        if (part < 2) {
            int k0t = 128 + part * 16;
            float w[16];
#pragma unroll
            for (int i = 0; i < 16; ++i) {
                int k = k0t + i;
                float x;
                if      (k < 132)  x = x_local[(size_t)eg * 4 + (k - 128)];
                else if (k < 148)  x = h_global[k - 132];
                else if (k < 152)  x = x_global[k - 148];
                else if (k == 152) x = tsc[0];
                else               x = 0.f;
                w[i] = x;
            }
            uint* dh2 = (uint*)(sAh + e * ASTR + k0t);
            uint* dl2 = (uint*)(sAl + e * ASTR + k0t);
#pragma unroll
            for (int i = 0; i < 8; ++i) {
                ushort h0, l0, h1, l1;
                bfsplit(w[2*i], h0, l0); bfsplit(w[2*i+1], h1, l1);
                dh2[i] = (uint)h0 | ((uint)h1 << 16);
                dl2[i] = (uint)l0 | ((uint)l1 << 16);
            }
        }
    }
    __syncthreads();
    // f MLP
    layer_p<5,8,false,false>(sAh, sAl, ASTR, wpk + F0_OFF, fb0, sHh, sHl, nullptr, nullptr, tid);
    __syncthreads();
    layer_p<4,8,true ,false>(sHh, sHl, HSTR, wpk + F1_OFF, fb1, sHh, sHl, nullptr, nullptr, tid);
    __syncthreads();
    layer_p<4,4,false,true >(sHh, sHl, HSTR, wpk + F2_OFF, fb2, nullptr, nullptr, out, s_af, tid);
    __syncthreads();
    // t MLP (sA planes intact)
    layer_p<5,8,false,false>(sAh, sAl, ASTR, wpk + T0_OFF, tb0, sHh, sHl, nullptr, nullptr, tid);
    __syncthreads();
    layer_p<4,8,true ,false>(sHh, sHl, HSTR, wpk + T1_OFF, tb1, sHh, sHl, nullptr, nullptr, tid);
    __syncthreads();
    layer_p<4,4,false,true >(sHh, sHl, HSTR, wpk + T2_OFF, tb2, nullptr, nullptr, out, s_at, tid);
}

// ================= gather fallback (R4, verified passing) =================
template<int KC, int NT, int KACT, bool SCATTER>
__device__ __forceinline__ void layer(
    const float* __restrict__ sA, int astr,
    const float* __restrict__ gW, const float* __restrict__ bias,
    float* __restrict__ sO,
    float* __restrict__ out, const int* __restrict__ s_nodes, int tid)
{
    constexpr int NTW = NT / 2;
    constexpr int N = NT * 16;
    const int lane = tid & 63;
    const int wave = tid >> 6;
    const int mt   = wave >> 1;
    const int ntb  = (wave & 1) * NTW;
    const int arow = mt * 16 + (lane & 15);
    const int kg   = (lane >> 4) * 8;
    const int nn   = lane & 15;

    f32x4 aHH[NTW], aLH[NTW], aHL[NTW];
#pragma unroll
    for (int i = 0; i < NTW; ++i)
#pragma unroll
        for (int r = 0; r < 4; ++r) { aHH[i][r] = 0.f; aLH[i][r] = 0.f; aHL[i][r] = 0.f; }

#pragma unroll
    for (int kc = 0; kc < KC; ++kc) {
        const float* ap = sA + arow * astr + kc * 32 + kg;
        float av[8];
        float4 a0 = *(const float4*)ap;
        float4 a1 = *(const float4*)(ap + 4);
        av[0]=a0.x; av[1]=a0.y; av[2]=a0.z; av[3]=a0.w;
        av[4]=a1.x; av[5]=a1.y; av[6]=a1.z; av[7]=a1.w;
        bf16x8 ah, al; split8(av, ah, al);
#pragma unroll
        for (int i = 0; i < NTW; ++i) {
            int n = (ntb + i) * 16 + nn;
            float wv[8];
#pragma unroll
            for (int j = 0; j < 8; ++j) {
                int k = kc * 32 + kg + j;
                float w = 0.f;
                if (KC * 32 <= KACT || k < KACT)
                    w = gW[(size_t)k * N + n];
                wv[j] = w;
            }
            bf16x8 bh, bl; split8(wv, bh, bl);
            aHH[i] = __builtin_amdgcn_mfma_f32_16x16x32_bf16(ah, bh, aHH[i], 0, 0, 0);
            aLH[i] = __builtin_amdgcn_mfma_f32_16x16x32_bf16(al, bh, aLH[i], 0, 0, 0);
            aHL[i] = __builtin_amdgcn_mfma_f32_16x16x32_bf16(ah, bl, aHL[i], 0, 0, 0);
        }
    }

    if (!SCATTER) __syncthreads();

#pragma unroll
    for (int i = 0; i < NTW; ++i) {
        int n = (ntb + i) * 16 + nn;
        float bv = bias[n];
#pragma unroll
        for (int r = 0; r < 4; ++r) {
            int m = mt * 16 + ((lane >> 4) << 2) + r;
            float h = ftanh(aHH[i][r] + aLH[i][r] + aHL[i][r] + bv);
            if (SCATTER) {
                unsafeAtomicAdd(out + (size_t)s_nodes[m] * 64 + n, h);
            } else {
                sO[m * SH + n] = h;
            }
        }
    }
}

__global__ __launch_bounds__(512) void edge_mlp_gather(
    const int* __restrict__ af_, const int* __restrict__ at_,
    const float* __restrict__ h_local, const float* __restrict__ h_global,
    const float* __restrict__ x_local, const float* __restrict__ x_global,
    const float* __restrict__ tsc,
    const float* __restrict__ fW0, const float* __restrict__ fb0,
    const float* __restrict__ fW1, const float* __restrict__ fb1,
    const float* __restrict__ fW2, const float* __restrict__ fb2,
    const float* __restrict__ tW0, const float* __restrict__ tb0,
    const float* __restrict__ tW1, const float* __restrict__ tb1,
    const float* __restrict__ tW2, const float* __restrict__ tb2,
    float* __restrict__ out)
{
    __shared__ float sA[TE * SA];
    __shared__ float sH[TE * SH];
    __shared__ int s_af[TE], s_at[TE];

    const int tid = threadIdx.x;
    const int e = tid >> 3, part = tid & 7;
    const int eg = blockIdx.x * TE + e;
    {
        int af = af_[eg], at = at_[eg];
        if (part == 0) { s_af[e] = af; s_at[e] = at; }
        int node = (part < 4) ? af : at;
        int k0 = ((part & 3) << 4) + ((part < 4) ? 0 : 64);
        const float4* hp = (const float4*)(h_local + (size_t)node * 64 + ((part & 3) << 4));
        float4* dst = (float4*)(sA + e * SA + k0);
        dst[0] = hp[0]; dst[1] = hp[1]; dst[2] = hp[2]; dst[3] = hp[3];
        if (part < 2) {
            int k0t = 128 + part * 16;
#pragma unroll
            for (int i = 0; i < 16; ++i) {
                int k = k0t + i;
                float x;
                if      (k < 132)  x = x_local[(size_t)eg * 4 + (k - 128)];
                else if (k < 148)  x = h_global[k - 132];
                else if (k < 152)  x = x_global[k - 148];
                else if (k == 152) x = tsc[0];
                else               x = 0.f;
                sA[e * SA + k] = x;
            }
        }
    }
    __syncthreads();
    layer<5,8,153,false>(sA, SA, fW0, fb0, sH, nullptr, nullptr, tid);
    __syncthreads();
    layer<4,8,128,false>(sH, SH, fW1, fb1, sH, nullptr, nullptr, tid);
    __syncthreads();
    layer<4,4,128,true >(sH, SH, fW2, fb2, nullptr, out, s_af, tid);
    __syncthreads();
    layer<5,8,153,false>(sA, SA, tW0, tb0, sH, nullptr, nullptr, tid);
    __syncthreads();
    layer<4,8,128,false>(sH, SH, tW1, tb1, sH, nullptr, nullptr, tid);
    __syncthreads();
    layer<4,4,128,true >(sH, SH, tW2, tb2, nullptr, out, s_at, tid);
}

__global__ __launch_bounds__(256) void tanh_kernel(float* __restrict__ out, int n4) {
    int i = blockIdx.x * blockDim.x + threadIdx.x;
    int stride = gridDim.x * blockDim.x;
    float4* p = (float4*)out;
    for (; i < n4; i += stride) {
        float4 v = p[i];
        v.x = ftanh(v.x); v.y = ftanh(v.y); v.z = ftanh(v.z); v.w = ftanh(v.w);
        p[i] = v;
    }
}

extern "C" void kernel_launch(void* const* d_in, const int* in_sizes, int n_in,
                              void* d_out, int out_size, void* d_ws, size_t ws_size,
                              hipStream_t stream) {
    const int*   addr_from = (const int*)d_in[0];
    const int*   addr_to   = (const int*)d_in[1];
    const float* h_local   = (const float*)d_in[2];
    const float* h_global  = (const float*)d_in[3];
    const float* x_local   = (const float*)d_in[4];
    const float* x_global  = (const float*)d_in[5];
    const float* tsc       = (const float*)d_in[6];
    const float* fW0 = (const float*)d_in[7];
    const float* fb0 = (const float*)d_in[8];
    const float* fW1 = (const float*)d_in[9];
    const float* fb1 = (const float*)d_in[10];
    const float* fW2 = (const float*)d_in[11];
    const float* fb2 = (const float*)d_in[12];
    const float* tW0 = (const float*)d_in[13];
    const float* tb0 = (const float*)d_in[14];
    const float* tW1 = (const float*)d_in[15];
    const float* tb1 = (const float*)d_in[16];
    const float* tW2 = (const float*)d_in[17];
    const float* tb2 = (const float*)d_in[18];
    float* out = (float*)d_out;

    hipMemsetAsync(d_out, 0, (size_t)NN * 64 * sizeof(float), stream);

    if (ws_size >= (size_t)WPK_BYTES) {
        ushort* wpk = (ushort*)d_ws;
        pack_w<<<WPK_TOTAL / 256, 256, 0, stream>>>(fW0, fW1, fW2, tW0, tW1, tW2, wpk);
        edge_mlp_packed<<<NE / TE, 512, 0, stream>>>(
            addr_from, addr_to, h_local, h_global, x_local, x_global, tsc,
            fb0, fb1, fb2, tb0, tb1, tb2, wpk, out);
    } else {
        edge_mlp_gather<<<NE / TE, 512, 0, stream>>>(
            addr_from, addr_to, h_local, h_global, x_local, x_global, tsc,
            fW0, fb0, fW1, fb1, fW2, fb2, tW0, tb0, tW1, tb1, tW2, tb2, out);
    }
    tanh_kernel<<<2048, 256, 0, stream>>>(out, NN * 64 / 4);
}

// Round 6
// 696.003 us; speedup vs baseline: 11.2026x; 1.1265x over previous
//
#include <hip/hip_runtime.h>

typedef unsigned int uint;
typedef unsigned short ushort;
typedef short bf16x8 __attribute__((ext_vector_type(8)));
typedef float f32x4 __attribute__((ext_vector_type(4)));
typedef uint u32x4 __attribute__((ext_vector_type(4)));

#define NE 800000
#define NN 100000
#define TE 64
#define ASTR 168   // ushort row stride of input planes (336 B, 21x16B)
#define HSTR 136   // ushort row stride of hidden planes (272 B, 17x16B)
#define SA 164     // f32 row stride (gather-fallback kernel)
#define SH 132

// packed-weight offsets (ushort elems) in d_ws. Layout per layer:
// offset(np,kc,plane,i) = (np*KC + kc)*2048 + plane*1024 + i*512 + lane*8 + j
// sizes: L0 (NP=4,KC=5)=40960, L1 (4,4)=32768, L2 (NP=2,KC=4)=16384
#define F0_OFF 0
#define F1_OFF 40960
#define F2_OFF 73728
#define T0_OFF 90112
#define T1_OFF 131072
#define T2_OFF 163840
#define WPK_TOTAL 180224
#define WPK_BYTES (WPK_TOTAL * 2)

__device__ __forceinline__ float ftanh(float x) {
    float cx = fminf(fmaxf(x, -15.f), 15.f);
    float e = __builtin_amdgcn_exp2f(cx * 2.885390081777927f);  // exp(2*cx)
    return (e - 1.f) * __builtin_amdgcn_rcpf(e + 1.f);
}

__device__ __forceinline__ void bfsplit(float x, ushort& hi, ushort& lo) {
    uint xb = __builtin_bit_cast(uint, x);
    hi = (ushort)(xb >> 16);
    float hif = __builtin_bit_cast(float, xb & 0xFFFF0000u);
    float res = x - hif;
    lo = (ushort)(__builtin_bit_cast(uint, res) >> 16);
}

__device__ __forceinline__ void split8(const float* v, bf16x8& fh, bf16x8& fl) {
    u32x4 H, L;
#pragma unroll
    for (int i = 0; i < 4; ++i) {
        ushort h0, l0, h1, l1;
        bfsplit(v[2*i],   h0, l0);
        bfsplit(v[2*i+1], h1, l1);
        H[i] = (uint)h0 | ((uint)h1 << 16);
        L[i] = (uint)l0 | ((uint)l1 << 16);
    }
    fh = __builtin_bit_cast(bf16x8, H);
    fl = __builtin_bit_cast(bf16x8, L);
}

// ---- weight pack (wave-contiguous layout) ----
// idx = base + (np*KC + kc)*2048 + plane*1024 + i*512 + lane*8 + j
// value = W[k = kc*32 + (lane>>4)*8 + j][n = np*32 + i*16 + (lane&15)]
__global__ __launch_bounds__(256) void pack_w(
    const float* __restrict__ fW0, const float* __restrict__ fW1, const float* __restrict__ fW2,
    const float* __restrict__ tW0, const float* __restrict__ tW1, const float* __restrict__ tW2,
    ushort* __restrict__ wpk)
{
    int idx = blockIdx.x * 256 + threadIdx.x;   // < WPK_TOTAL
    const float* src; int NP, KC, Kact, base;
    if      (idx < F1_OFF) { src = fW0; NP = 4; KC = 5; Kact = 153; base = F0_OFF; }
    else if (idx < F2_OFF) { src = fW1; NP = 4; KC = 4; Kact = 128; base = F1_OFF; }
    else if (idx < T0_OFF) { src = fW2; NP = 2; KC = 4; Kact = 128; base = F2_OFF; }
    else if (idx < T1_OFF) { src = tW0; NP = 4; KC = 5; Kact = 153; base = T0_OFF; }
    else if (idx < T2_OFF) { src = tW1; NP = 4; KC = 4; Kact = 128; base = T1_OFF; }
    else                   { src = tW2; NP = 2; KC = 4; Kact = 128; base = T2_OFF; }
    int rel   = idx - base;
    int j     = rel & 7;
    int lane  = (rel >> 3) & 63;
    int sub   = rel >> 9;
    int i     = sub & 1;
    int plane = (sub >> 1) & 1;
    int s2    = sub >> 2;
    int kc    = s2 % KC;
    int np    = s2 / KC;
    int k = kc * 32 + ((lane >> 4) << 3) + j;
    int n = np * 32 + i * 16 + (lane & 15);
    int N = NP * 32;
    float w = (k < Kact) ? src[(size_t)k * N + n] : 0.f;
    ushort hi, lo; bfsplit(w, hi, lo);
    wpk[idx] = plane ? lo : hi;
}

// ================= packed-weight main kernel =================
// 8 waves: mt = wave>>2 (32 edge rows), np = wave&3 (32-col pair), active if np<NP.
// Per kc: 4 ds_read_b128 (A hi/lo x 2 mi) + 4 global dwordx4 (W, contiguous 4KB
// window) + 12 MFMA (2mi x 2ni x 3 chains).
template<int KC, int NP, bool INPLACE, bool SCATTER>
__device__ __forceinline__ void layer_p(
    const ushort* __restrict__ sAh, const ushort* __restrict__ sAl, int astr,
    const ushort* __restrict__ gW, const float* __restrict__ bias,
    ushort* __restrict__ sOh, ushort* __restrict__ sOl,
    float* __restrict__ out, const int* __restrict__ s_nodes, int tid)
{
    const int lane = tid & 63;
    const int wave = tid >> 6;
    const int mt   = wave >> 2;          // 0..1
    const int np   = wave & 3;           // 0..3
    const bool active = (np < NP);
    const int nn   = lane & 15;
    const int kg   = ((lane >> 4) & 3) << 3;
    const ushort* apH = sAh + (mt * 32 + nn) * astr + kg;
    const ushort* apL = sAl + (mt * 32 + nn) * astr + kg;
    const ushort* gWw = gW + (size_t)np * KC * 2048 + lane * 8;

    f32x4 aHH[2][2], aLH[2][2], aHL[2][2];
#pragma unroll
    for (int mi = 0; mi < 2; ++mi)
#pragma unroll
        for (int ni = 0; ni < 2; ++ni)
#pragma unroll
            for (int r = 0; r < 4; ++r) {
                aHH[mi][ni][r] = 0.f; aLH[mi][ni][r] = 0.f; aHL[mi][ni][r] = 0.f;
            }

    if (active) {
#pragma unroll
        for (int kc = 0; kc < KC; ++kc) {
            bf16x8 ah[2], al[2], bh[2], bl[2];
            ah[0] = *(const bf16x8*)(apH + kc * 32);
            ah[1] = *(const bf16x8*)(apH + 16 * astr + kc * 32);
            al[0] = *(const bf16x8*)(apL + kc * 32);
            al[1] = *(const bf16x8*)(apL + 16 * astr + kc * 32);
            bh[0] = *(const bf16x8*)(gWw + kc * 2048);
            bh[1] = *(const bf16x8*)(gWw + kc * 2048 + 512);
            bl[0] = *(const bf16x8*)(gWw + kc * 2048 + 1024);
            bl[1] = *(const bf16x8*)(gWw + kc * 2048 + 1536);
#pragma unroll
            for (int mi = 0; mi < 2; ++mi)
#pragma unroll
                for (int ni = 0; ni < 2; ++ni) {
                    aHH[mi][ni] = __builtin_amdgcn_mfma_f32_16x16x32_bf16(ah[mi], bh[ni], aHH[mi][ni], 0, 0, 0);
                    aLH[mi][ni] = __builtin_amdgcn_mfma_f32_16x16x32_bf16(al[mi], bh[ni], aLH[mi][ni], 0, 0, 0);
                    aHL[mi][ni] = __builtin_amdgcn_mfma_f32_16x16x32_bf16(ah[mi], bl[ni], aHL[mi][ni], 0, 0, 0);
                }
        }
    }

    if (INPLACE) __syncthreads();   // all reads of sO done before overwrite

    if (active) {
#pragma unroll
        for (int mi = 0; mi < 2; ++mi)
#pragma unroll
            for (int ni = 0; ni < 2; ++ni) {
                int n = np * 32 + ni * 16 + nn;
                float bv = bias[n];
#pragma unroll
                for (int r = 0; r < 4; ++r) {
                    int m = mt * 32 + mi * 16 + ((lane >> 4) << 2) + r;  // C/D row map
                    float h = ftanh(aHH[mi][ni][r] + aLH[mi][ni][r] + aHL[mi][ni][r] + bv);
                    if (SCATTER) {
                        unsafeAtomicAdd(out + (size_t)s_nodes[m] * 64 + n, h);
                    } else {
                        ushort hi, lo; bfsplit(h, hi, lo);
                        sOh[m * HSTR + n] = hi;
                        sOl[m * HSTR + n] = lo;
                    }
                }
            }
    }
}

__global__ __launch_bounds__(512, 4) void edge_mlp_packed(
    const int* __restrict__ af_, const int* __restrict__ at_,
    const float* __restrict__ h_local, const float* __restrict__ h_global,
    const float* __restrict__ x_local, const float* __restrict__ x_global,
    const float* __restrict__ tsc,
    const float* __restrict__ fb0, const float* __restrict__ fb1, const float* __restrict__ fb2,
    const float* __restrict__ tb0, const float* __restrict__ tb1, const float* __restrict__ tb2,
    const ushort* __restrict__ wpk, float* __restrict__ out)
{
    __shared__ ushort sAh[TE * ASTR], sAl[TE * ASTR];   // 21504 B each
    __shared__ ushort sHh[TE * HSTR], sHl[TE * HSTR];   // 17408 B each
    __shared__ int s_af[TE], s_at[TE];                  // total 78336 B

    const int tid = threadIdx.x;
    const int e = tid >> 3, part = tid & 7;
    const int eg = blockIdx.x * TE + e;
    {
        int af = af_[eg], at = at_[eg];
        if (part == 0) { s_af[e] = af; s_at[e] = at; }
        int node = (part < 4) ? af : at;
        int k0 = ((part & 3) << 4) + ((part < 4) ? 0 : 64);
        const float4* hp = (const float4*)(h_local + (size_t)node * 64 + ((part & 3) << 4));
        float4 q0 = hp[0], q1 = hp[1], q2 = hp[2], q3 = hp[3];
        float v[16] = {q0.x,q0.y,q0.z,q0.w, q1.x,q1.y,q1.z,q1.w,
                       q2.x,q2.y,q2.z,q2.w, q3.x,q3.y,q3.z,q3.w};
        u32x4 H0, H1, L0, L1;
#pragma unroll
        for (int i = 0; i < 4; ++i) {
            ushort h0, l0, h1, l1;
            bfsplit(v[2*i], h0, l0); bfsplit(v[2*i+1], h1, l1);
            H0[i] = (uint)h0 | ((uint)h1 << 16);
            L0[i] = (uint)l0 | ((uint)l1 << 16);
        }
#pragma unroll
        for (int i = 0; i < 4; ++i) {
            ushort h0, l0, h1, l1;
            bfsplit(v[8+2*i], h0, l0); bfsplit(v[8+2*i+1], h1, l1);
            H1[i] = (uint)h0 | ((uint)h1 << 16);
            L1[i] = (uint)l0 | ((uint)l1 << 16);
        }
        *(u32x4*)(sAh + e * ASTR + k0)     = H0;
        *(u32x4*)(sAh + e * ASTR + k0 + 8) = H1;
        *(u32x4*)(sAl + e * ASTR + k0)     = L0;
        *(u32x4*)(sAl + e * ASTR + k0 + 8) = L1;
        if (part < 2) {
            int k0t = 128 + part * 16;
            float w[16];
#pragma unroll
            for (int i = 0; i < 16; ++i) {
                int k = k0t + i;
                float x;
                if      (k < 132)  x = x_local[(size_t)eg * 4 + (k - 128)];
                else if (k < 148)  x = h_global[k - 132];
                else if (k < 152)  x = x_global[k - 148];
                else if (k == 152) x = tsc[0];
                else               x = 0.f;
                w[i] = x;
            }
            u32x4 H2, H3, L2, L3;
#pragma unroll
            for (int i = 0; i < 4; ++i) {
                ushort h0, l0, h1, l1;
                bfsplit(w[2*i], h0, l0); bfsplit(w[2*i+1], h1, l1);
                H2[i] = (uint)h0 | ((uint)h1 << 16);
                L2[i] = (uint)l0 | ((uint)l1 << 16);
            }
#pragma unroll
            for (int i = 0; i < 4; ++i) {
                ushort h0, l0, h1, l1;
                bfsplit(w[8+2*i], h0, l0); bfsplit(w[8+2*i+1], h1, l1);
                H3[i] = (uint)h0 | ((uint)h1 << 16);
                L3[i] = (uint)l0 | ((uint)l1 << 16);
            }
            *(u32x4*)(sAh + e * ASTR + k0t)     = H2;
            *(u32x4*)(sAh + e * ASTR + k0t + 8) = H3;
            *(u32x4*)(sAl + e * ASTR + k0t)     = L2;
            *(u32x4*)(sAl + e * ASTR + k0t + 8) = L3;
        }
    }
    __syncthreads();
    // f MLP
    layer_p<5,4,false,false>(sAh, sAl, ASTR, wpk + F0_OFF, fb0, sHh, sHl, nullptr, nullptr, tid);
    __syncthreads();
    layer_p<4,4,true ,false>(sHh, sHl, HSTR, wpk + F1_OFF, fb1, sHh, sHl, nullptr, nullptr, tid);
    __syncthreads();
    layer_p<4,2,false,true >(sHh, sHl, HSTR, wpk + F2_OFF, fb2, nullptr, nullptr, out, s_af, tid);
    __syncthreads();
    // t MLP (sA planes intact)
    layer_p<5,4,false,false>(sAh, sAl, ASTR, wpk + T0_OFF, tb0, sHh, sHl, nullptr, nullptr, tid);
    __syncthreads();
    layer_p<4,4,true ,false>(sHh, sHl, HSTR, wpk + T1_OFF, tb1, sHh, sHl, nullptr, nullptr, tid);
    __syncthreads();
    layer_p<4,2,false,true >(sHh, sHl, HSTR, wpk + T2_OFF, tb2, nullptr, nullptr, out, s_at, tid);
}

// ================= gather fallback (R4, verified passing) =================
template<int KC, int NT, int KACT, bool SCATTER>
__device__ __forceinline__ void layer(
    const float* __restrict__ sA, int astr,
    const float* __restrict__ gW, const float* __restrict__ bias,
    float* __restrict__ sO,
    float* __restrict__ out, const int* __restrict__ s_nodes, int tid)
{
    constexpr int NTW = NT / 2;
    constexpr int N = NT * 16;
    const int lane = tid & 63;
    const int wave = tid >> 6;
    const int mt   = wave >> 1;
    const int ntb  = (wave & 1) * NTW;
    const int arow = mt * 16 + (lane & 15);
    const int kg   = (lane >> 4) * 8;
    const int nn   = lane & 15;

    f32x4 aHH[NTW], aLH[NTW], aHL[NTW];
#pragma unroll
    for (int i = 0; i < NTW; ++i)
#pragma unroll
        for (int r = 0; r < 4; ++r) { aHH[i][r] = 0.f; aLH[i][r] = 0.f; aHL[i][r] = 0.f; }

#pragma unroll
    for (int kc = 0; kc < KC; ++kc) {
        const float* ap = sA + arow * astr + kc * 32 + kg;
        float av[8];
        float4 a0 = *(const float4*)ap;
        float4 a1 = *(const float4*)(ap + 4);
        av[0]=a0.x; av[1]=a0.y; av[2]=a0.z; av[3]=a0.w;
        av[4]=a1.x; av[5]=a1.y; av[6]=a1.z; av[7]=a1.w;
        bf16x8 ah, al; split8(av, ah, al);
#pragma unroll
        for (int i = 0; i < NTW; ++i) {
            int n = (ntb + i) * 16 + nn;
            float wv[8];
#pragma unroll
            for (int j = 0; j < 8; ++j) {
                int k = kc * 32 + kg + j;
                float w = 0.f;
                if (KC * 32 <= KACT || k < KACT)
                    w = gW[(size_t)k * N + n];
                wv[j] = w;
            }
            bf16x8 bh, bl; split8(wv, bh, bl);
            aHH[i] = __builtin_amdgcn_mfma_f32_16x16x32_bf16(ah, bh, aHH[i], 0, 0, 0);
            aLH[i] = __builtin_amdgcn_mfma_f32_16x16x32_bf16(al, bh, aLH[i], 0, 0, 0);
            aHL[i] = __builtin_amdgcn_mfma_f32_16x16x32_bf16(ah, bl, aHL[i], 0, 0, 0);
        }
    }

    if (!SCATTER) __syncthreads();

#pragma unroll
    for (int i = 0; i < NTW; ++i) {
        int n = (ntb + i) * 16 + nn;
        float bv = bias[n];
#pragma unroll
        for (int r = 0; r < 4; ++r) {
            int m = mt * 16 + ((lane >> 4) << 2) + r;
            float h = ftanh(aHH[i][r] + aLH[i][r] + aHL[i][r] + bv);
            if (SCATTER) {
                unsafeAtomicAdd(out + (size_t)s_nodes[m] * 64 + n, h);
            } else {
                sO[m * SH + n] = h;
            }
        }
    }
}

__global__ __launch_bounds__(512) void edge_mlp_gather(
    const int* __restrict__ af_, const int* __restrict__ at_,
    const float* __restrict__ h_local, const float* __restrict__ h_global,
    const float* __restrict__ x_local, const float* __restrict__ x_global,
    const float* __restrict__ tsc,
    const float* __restrict__ fW0, const float* __restrict__ fb0,
    const float* __restrict__ fW1, const float* __restrict__ fb1,
    const float* __restrict__ fW2, const float* __restrict__ fb2,
    const float* __restrict__ tW0, const float* __restrict__ tb0,
    const float* __restrict__ tW1, const float* __restrict__ tb1,
    const float* __restrict__ tW2, const float* __restrict__ tb2,
    float* __restrict__ out)
{
    __shared__ float sA[TE * SA];
    __shared__ float sH[TE * SH];
    __shared__ int s_af[TE], s_at[TE];

    const int tid = threadIdx.x;
    const int e = tid >> 3, part = tid & 7;
    const int eg = blockIdx.x * TE + e;
    {
        int af = af_[eg], at = at_[eg];
        if (part == 0) { s_af[e] = af; s_at[e] = at; }
        int node = (part < 4) ? af : at;
        int k0 = ((part & 3) << 4) + ((part < 4) ? 0 : 64);
        const float4* hp = (const float4*)(h_local + (size_t)node * 64 + ((part & 3) << 4));
        float4* dst = (float4*)(sA + e * SA + k0);
        dst[0] = hp[0]; dst[1] = hp[1]; dst[2] = hp[2]; dst[3] = hp[3];
        if (part < 2) {
            int k0t = 128 + part * 16;
#pragma unroll
            for (int i = 0; i < 16; ++i) {
                int k = k0t + i;
                float x;
                if      (k < 132)  x = x_local[(size_t)eg * 4 + (k - 128)];
                else if (k < 148)  x = h_global[k - 132];
                else if (k < 152)  x = x_global[k - 148];
                else if (k == 152) x = tsc[0];
                else               x = 0.f;
                sA[e * SA + k] = x;
            }
        }
    }
    __syncthreads();
    layer<5,8,153,false>(sA, SA, fW0, fb0, sH, nullptr, nullptr, tid);
    __syncthreads();
    layer<4,8,128,false>(sH, SH, fW1, fb1, sH, nullptr, nullptr, tid);
    __syncthreads();
    layer<4,4,128,true >(sH, SH, fW2, fb2, nullptr, out, s_af, tid);
    __syncthreads();
    layer<5,8,153,false>(sA, SA, tW0, tb0, sH, nullptr, nullptr, tid);
    __syncthreads();
    layer<4,8,128,false>(sH, SH, tW1, tb1, sH, nullptr, nullptr, tid);
    __syncthreads();
    layer<4,4,128,true >(sH, SH, tW2, tb2, nullptr, out, s_at, tid);
}

__global__ __launch_bounds__(256) void tanh_kernel(float* __restrict__ out, int n4) {
    int i = blockIdx.x * blockDim.x + threadIdx.x;
    int stride = gridDim.x * blockDim.x;
    float4* p = (float4*)out;
    for (; i < n4; i += stride) {
        float4 v = p[i];
        v.x = ftanh(v.x); v.y = ftanh(v.y); v.z = ftanh(v.z); v.w = ftanh(v.w);
        p[i] = v;
    }
}

extern "C" void kernel_launch(void* const* d_in, const int* in_sizes, int n_in,
                              void* d_out, int out_size, void* d_ws, size_t ws_size,
                              hipStream_t stream) {
    const int*   addr_from = (const int*)d_in[0];
    const int*   addr_to   = (const int*)d_in[1];
    const float* h_local   = (const float*)d_in[2];
    const float* h_global  = (const float*)d_in[3];
    const float* x_local   = (const float*)d_in[4];
    const float* x_global  = (const float*)d_in[5];
    const float* tsc       = (const float*)d_in[6];
    const float* fW0 = (const float*)d_in[7];
    const float* fb0 = (const float*)d_in[8];
    const float* fW1 = (const float*)d_in[9];
    const float* fb1 = (const float*)d_in[10];
    const float* fW2 = (const float*)d_in[11];
    const float* fb2 = (const float*)d_in[12];
    const float* tW0 = (const float*)d_in[13];
    const float* tb0 = (const float*)d_in[14];
    const float* tW1 = (const float*)d_in[15];
    const float* tb1 = (const float*)d_in[16];
    const float* tW2 = (const float*)d_in[17];
    const float* tb2 = (const float*)d_in[18];
    float* out = (float*)d_out;

    hipMemsetAsync(d_out, 0, (size_t)NN * 64 * sizeof(float), stream);

    if (ws_size >= (size_t)WPK_BYTES) {
        ushort* wpk = (ushort*)d_ws;
        pack_w<<<WPK_TOTAL / 256, 256, 0, stream>>>(fW0, fW1, fW2, tW0, tW1, tW2, wpk);
        edge_mlp_packed<<<NE / TE, 512, 0, stream>>>(
            addr_from, addr_to, h_local, h_global, x_local, x_global, tsc,
            fb0, fb1, fb2, tb0, tb1, tb2, wpk, out);
    } else {
        edge_mlp_gather<<<NE / TE, 512, 0, stream>>>(
            addr_from, addr_to, h_local, h_global, x_local, x_global, tsc,
            fW0, fb0, fW1, fb1, fW2, fb2, tW0, tb0, tW1, tb1, tW2, tb2, out);
    }
    tanh_kernel<<<2048, 256, 0, stream>>>(out, NN * 64 / 4);
}

// Round 8
// 614.334 us; speedup vs baseline: 12.6919x; 1.1329x over previous
//
#include <hip/hip_runtime.h>
#include <hip/hip_bf16.h>

typedef unsigned int uint;
typedef unsigned short ushort;
typedef short bf16x8 __attribute__((ext_vector_type(8)));
typedef float f32x4 __attribute__((ext_vector_type(4)));
typedef uint u32x4 __attribute__((ext_vector_type(4)));

#define NE 800000
#define NN 100000
#define TE 64
#define ASTR 168   // ushort row stride of input planes (336 B, 21x16B)
#define HSTR 136   // ushort row stride of hidden planes (272 B, 17x16B)
#define SA 164     // f32 row stride (gather-fallback kernel)
#define SH 132

// packed-weight offsets (ushort elems) in d_ws. Layout per layer:
// offset(np,kc,plane,i) = (np*KC + kc)*2048 + plane*1024 + i*512 + lane*8 + j
#define F0_OFF 0
#define F1_OFF 40960
#define F2_OFF 73728
#define T0_OFF 90112
#define T1_OFF 131072
#define T2_OFF 163840
#define WPK_TOTAL 180224
#define WPK_BYTES (WPK_TOTAL * 2)

__device__ __forceinline__ float ftanh(float x) {
    float cx = fminf(fmaxf(x, -15.f), 15.f);
    float e = __builtin_amdgcn_exp2f(cx * 2.885390081777927f);  // exp(2*cx)
    return (e - 1.f) * __builtin_amdgcn_rcpf(e + 1.f);
}

__device__ __forceinline__ void bfsplit(float x, ushort& hi, ushort& lo) {
    uint xb = __builtin_bit_cast(uint, x);
    hi = (ushort)(xb >> 16);
    float hif = __builtin_bit_cast(float, xb & 0xFFFF0000u);
    float res = x - hif;
    lo = (ushort)(__builtin_bit_cast(uint, res) >> 16);
}

__device__ __forceinline__ void split8(const float* v, bf16x8& fh, bf16x8& fl) {
    u32x4 H, L;
#pragma unroll
    for (int i = 0; i < 4; ++i) {
        ushort h0, l0, h1, l1;
        bfsplit(v[2*i],   h0, l0);
        bfsplit(v[2*i+1], h1, l1);
        H[i] = (uint)h0 | ((uint)h1 << 16);
        L[i] = (uint)l0 | ((uint)l1 << 16);
    }
    fh = __builtin_bit_cast(bf16x8, H);
    fl = __builtin_bit_cast(bf16x8, L);
}

// ---- weight pack (wave-contiguous layout) — unchanged from R6 (verified) ----
__global__ __launch_bounds__(256) void pack_w(
    const float* __restrict__ fW0, const float* __restrict__ fW1, const float* __restrict__ fW2,
    const float* __restrict__ tW0, const float* __restrict__ tW1, const float* __restrict__ tW2,
    ushort* __restrict__ wpk)
{
    int idx = blockIdx.x * 256 + threadIdx.x;   // < WPK_TOTAL
    const float* src; int NP, KC, Kact, base;
    if      (idx < F1_OFF) { src = fW0; NP = 4; KC = 5; Kact = 153; base = F0_OFF; }
    else if (idx < F2_OFF) { src = fW1; NP = 4; KC = 4; Kact = 128; base = F1_OFF; }
    else if (idx < T0_OFF) { src = fW2; NP = 2; KC = 4; Kact = 128; base = F2_OFF; }
    else if (idx < T1_OFF) { src = tW0; NP = 4; KC = 5; Kact = 153; base = T0_OFF; }
    else if (idx < T2_OFF) { src = tW1; NP = 4; KC = 4; Kact = 128; base = T1_OFF; }
    else                   { src = tW2; NP = 2; KC = 4; Kact = 128; base = T2_OFF; }
    int rel   = idx - base;
    int j     = rel & 7;
    int lane  = (rel >> 3) & 63;
    int sub   = rel >> 9;
    int i     = sub & 1;
    int plane = (sub >> 1) & 1;
    int s2    = sub >> 2;
    int kc    = s2 % KC;
    int np    = s2 / KC;
    int k = kc * 32 + ((lane >> 4) << 3) + j;
    int n = np * 32 + i * 16 + (lane & 15);
    int N = NP * 32;
    float w = (k < Kact) ? src[(size_t)k * N + n] : 0.f;
    ushort hi, lo; bfsplit(w, hi, lo);
    wpk[idx] = plane ? lo : hi;
}

// ================= packed-weight main kernel =================
// 8 waves: mt = wave>>2 (32 edge rows), np = wave&3 (32-col pair), active if np<NP.
// Register-pipelined: depth-2 W prefetch into 3 rotating buffers (prefetch
// target (kc+2)%3 is provably != in-use kc%3), depth-1 A double-buffer.
// Chains: accM = bias + Ah*Wh; accC = Al*Wh + Ah*Wl (merged accumulator).
template<int KC, int NP, bool INPLACE, bool SCATTER>
__device__ __forceinline__ void layer_p(
    const ushort* __restrict__ sAh, const ushort* __restrict__ sAl, int astr,
    const ushort* __restrict__ gW, const float* __restrict__ bias,
    ushort* __restrict__ sOh, ushort* __restrict__ sOl,
    float* __restrict__ out, const int* __restrict__ s_nodes, int tid)
{
    const int lane = tid & 63;
    const int wave = tid >> 6;
    const int mt   = wave >> 2;          // 0..1
    const int np   = wave & 3;           // 0..3
    const bool active = (np < NP);
    const int nn   = lane & 15;
    const int kq   = (lane >> 4) & 3;
    const ushort* apH = sAh + (mt * 32 + nn) * astr + kq * 8;
    const ushort* apL = sAl + (mt * 32 + nn) * astr + kq * 8;

    f32x4 accM[2][2], accC[2][2];

    if (active) {
        const int npu = __builtin_amdgcn_readfirstlane(np);
        const ushort* gWl = gW + (size_t)npu * (KC * 2048) + lane * 8;

        // bias into main accumulator, corr chain zero
#pragma unroll
        for (int mi = 0; mi < 2; ++mi)
#pragma unroll
            for (int ni = 0; ni < 2; ++ni) {
                float bv = bias[np * 32 + ni * 16 + nn];
#pragma unroll
                for (int r = 0; r < 4; ++r) { accM[mi][ni][r] = bv; accC[mi][ni][r] = 0.f; }
            }

        bf16x8 wb[3][4];
        bf16x8 ab[2][4];   // [buf][0]=ah mi0, [1]=ah mi1, [2]=al mi0, [3]=al mi1
        // prologue: W chunks 0,1 (depth-2), A chunk 0
#pragma unroll
        for (int d = 0; d < 2; ++d) {
            if (d < KC) {
#pragma unroll
                for (int j = 0; j < 4; ++j)
                    wb[d][j] = *(const bf16x8*)(gWl + d * 2048 + j * 512);
            }
        }
        ab[0][0] = *(const bf16x8*)(apH);
        ab[0][1] = *(const bf16x8*)(apH + 16 * astr);
        ab[0][2] = *(const bf16x8*)(apL);
        ab[0][3] = *(const bf16x8*)(apL + 16 * astr);

#pragma unroll
        for (int kc = 0; kc < KC; ++kc) {
            const int cw = kc % 3;
            const int ca = kc & 1;
            if (kc + 2 < KC) {
                // prefetch W chunk kc+2 into wb[(kc+2)%3] — distinct from wb[cw]
#pragma unroll
                for (int j = 0; j < 4; ++j)
                    wb[(kc + 2) % 3][j] = *(const bf16x8*)(gWl + (kc + 2) * 2048 + j * 512);
            }
            if (kc + 1 < KC) {
                ab[ca ^ 1][0] = *(const bf16x8*)(apH + (kc + 1) * 32);
                ab[ca ^ 1][1] = *(const bf16x8*)(apH + 16 * astr + (kc + 1) * 32);
                ab[ca ^ 1][2] = *(const bf16x8*)(apL + (kc + 1) * 32);
                ab[ca ^ 1][3] = *(const bf16x8*)(apL + 16 * astr + (kc + 1) * 32);
            }
#pragma unroll
            for (int mi = 0; mi < 2; ++mi)
#pragma unroll
                for (int ni = 0; ni < 2; ++ni)
                    accM[mi][ni] = __builtin_amdgcn_mfma_f32_16x16x32_bf16(ab[ca][mi], wb[cw][ni], accM[mi][ni], 0, 0, 0);
#pragma unroll
            for (int mi = 0; mi < 2; ++mi)
#pragma unroll
                for (int ni = 0; ni < 2; ++ni) {
                    accC[mi][ni] = __builtin_amdgcn_mfma_f32_16x16x32_bf16(ab[ca][2 + mi], wb[cw][ni], accC[mi][ni], 0, 0, 0);
                    accC[mi][ni] = __builtin_amdgcn_mfma_f32_16x16x32_bf16(ab[ca][mi], wb[cw][2 + ni], accC[mi][ni], 0, 0, 0);
                }
        }
    }

    if (INPLACE) __syncthreads();   // all reads of sO done before overwrite

    if (active) {
#pragma unroll
        for (int mi = 0; mi < 2; ++mi)
#pragma unroll
            for (int ni = 0; ni < 2; ++ni) {
                int n = np * 32 + ni * 16 + nn;
#pragma unroll
                for (int r = 0; r < 4; ++r) {
                    int m = mt * 32 + mi * 16 + kq * 4 + r;  // C/D row map
                    float h = ftanh(accM[mi][ni][r] + accC[mi][ni][r]);
                    if (SCATTER) {
                        unsafeAtomicAdd(out + (size_t)s_nodes[m] * 64 + n, h);
                    } else {
                        ushort hi, lo; bfsplit(h, hi, lo);
                        sOh[m * HSTR + n] = hi;
                        sOl[m * HSTR + n] = lo;
                    }
                }
            }
    }
}

__global__ __launch_bounds__(512, 4) void edge_mlp_packed(
    const int* __restrict__ af_, const int* __restrict__ at_,
    const float* __restrict__ h_local, const float* __restrict__ h_global,
    const float* __restrict__ x_local, const float* __restrict__ x_global,
    const float* __restrict__ tsc,
    const float* __restrict__ fb0, const float* __restrict__ fb1, const float* __restrict__ fb2,
    const float* __restrict__ tb0, const float* __restrict__ tb1, const float* __restrict__ tb2,
    const ushort* __restrict__ wpk, float* __restrict__ out)
{
    __shared__ ushort sAh[TE * ASTR], sAl[TE * ASTR];   // 21504 B each
    __shared__ ushort sHh[TE * HSTR], sHl[TE * HSTR];   // 17408 B each
    __shared__ int s_af[TE], s_at[TE];                  // total 78336 B

    const int tid = threadIdx.x;
    const int e = tid >> 3, part = tid & 7;
    const int eg = blockIdx.x * TE + e;
    {
        int af = af_[eg], at = at_[eg];
        if (part == 0) { s_af[e] = af; s_at[e] = at; }
        int node = (part < 4) ? af : at;
        int k0 = ((part & 3) << 4) + ((part < 4) ? 0 : 64);
        const float4* hp = (const float4*)(h_local + (size_t)node * 64 + ((part & 3) << 4));
        float4 q0 = hp[0], q1 = hp[1], q2 = hp[2], q3 = hp[3];
        float v[16] = {q0.x,q0.y,q0.z,q0.w, q1.x,q1.y,q1.z,q1.w,
                       q2.x,q2.y,q2.z,q2.w, q3.x,q3.y,q3.z,q3.w};
        u32x4 H0, H1, L0, L1;
#pragma unroll
        for (int i = 0; i < 4; ++i) {
            ushort h0, l0, h1, l1;
            bfsplit(v[2*i], h0, l0); bfsplit(v[2*i+1], h1, l1);
            H0[i] = (uint)h0 | ((uint)h1 << 16);
            L0[i] = (uint)l0 | ((uint)l1 << 16);
        }
#pragma unroll
        for (int i = 0; i < 4; ++i) {
            ushort h0, l0, h1, l1;
            bfsplit(v[8+2*i], h0, l0); bfsplit(v[8+2*i+1], h1, l1);
            H1[i] = (uint)h0 | ((uint)h1 << 16);
            L1[i] = (uint)l0 | ((uint)l1 << 16);
        }
        *(u32x4*)(sAh + e * ASTR + k0)     = H0;
        *(u32x4*)(sAh + e * ASTR + k0 + 8) = H1;
        *(u32x4*)(sAl + e * ASTR + k0)     = L0;
        *(u32x4*)(sAl + e * ASTR + k0 + 8) = L1;
        if (part < 2) {
            int k0t = 128 + part * 16;
            float w[16];
#pragma unroll
            for (int i = 0; i < 16; ++i) {
                int k = k0t + i;
                float x;
                if      (k < 132)  x = x_local[(size_t)eg * 4 + (k - 128)];
                else if (k < 148)  x = h_global[k - 132];
                else if (k < 152)  x = x_global[k - 148];
                else if (k == 152) x = tsc[0];
                else               x = 0.f;
                w[i] = x;
            }
            u32x4 H2, H3, L2, L3;
#pragma unroll
            for (int i = 0; i < 4; ++i) {
                ushort h0, l0, h1, l1;
                bfsplit(w[2*i], h0, l0); bfsplit(w[2*i+1], h1, l1);
                H2[i] = (uint)h0 | ((uint)h1 << 16);
                L2[i] = (uint)l0 | ((uint)l1 << 16);
            }
#pragma unroll
            for (int i = 0; i < 4; ++i) {
                ushort h0, l0, h1, l1;
                bfsplit(w[8+2*i], h0, l0); bfsplit(w[8+2*i+1], h1, l1);
                H3[i] = (uint)h0 | ((uint)h1 << 16);
                L3[i] = (uint)l0 | ((uint)l1 << 16);
            }
            *(u32x4*)(sAh + e * ASTR + k0t)     = H2;
            *(u32x4*)(sAh + e * ASTR + k0t + 8) = H3;
            *(u32x4*)(sAl + e * ASTR + k0t)     = L2;
            *(u32x4*)(sAl + e * ASTR + k0t + 8) = L3;
        }
    }
    __syncthreads();
    // f MLP
    layer_p<5,4,false,false>(sAh, sAl, ASTR, wpk + F0_OFF, fb0, sHh, sHl, nullptr, nullptr, tid);
    __syncthreads();
    layer_p<4,4,true ,false>(sHh, sHl, HSTR, wpk + F1_OFF, fb1, sHh, sHl, nullptr, nullptr, tid);
    __syncthreads();
    layer_p<4,2,false,true >(sHh, sHl, HSTR, wpk + F2_OFF, fb2, nullptr, nullptr, out, s_af, tid);
    __syncthreads();
    // t MLP (sA planes intact)
    layer_p<5,4,false,false>(sAh, sAl, ASTR, wpk + T0_OFF, tb0, sHh, sHl, nullptr, nullptr, tid);
    __syncthreads();
    layer_p<4,4,true ,false>(sHh, sHl, HSTR, wpk + T1_OFF, tb1, sHh, sHl, nullptr, nullptr, tid);
    __syncthreads();
    layer_p<4,2,false,true >(sHh, sHl, HSTR, wpk + T2_OFF, tb2, nullptr, nullptr, out, s_at, tid);
}

// ================= gather fallback (R4, verified passing) =================
template<int KC, int NT, int KACT, bool SCATTER>
__device__ __forceinline__ void layer(
    const float* __restrict__ sA, int astr,
    const float* __restrict__ gW, const float* __restrict__ bias,
    float* __restrict__ sO,
    float* __restrict__ out, const int* __restrict__ s_nodes, int tid)
{
    constexpr int NTW = NT / 2;
    constexpr int N = NT * 16;
    const int lane = tid & 63;
    const int wave = tid >> 6;
    const int mt   = wave >> 1;
    const int ntb  = (wave & 1) * NTW;
    const int arow = mt * 16 + (lane & 15);
    const int kg   = (lane >> 4) * 8;
    const int nn   = lane & 15;

    f32x4 aHH[NTW], aLH[NTW], aHL[NTW];
#pragma unroll
    for (int i = 0; i < NTW; ++i)
#pragma unroll
        for (int r = 0; r < 4; ++r) { aHH[i][r] = 0.f; aLH[i][r] = 0.f; aHL[i][r] = 0.f; }

#pragma unroll
    for (int kc = 0; kc < KC; ++kc) {
        const float* ap = sA + arow * astr + kc * 32 + kg;
        float av[8];
        float4 a0 = *(const float4*)ap;
        float4 a1 = *(const float4*)(ap + 4);
        av[0]=a0.x; av[1]=a0.y; av[2]=a0.z; av[3]=a0.w;
        av[4]=a1.x; av[5]=a1.y; av[6]=a1.z; av[7]=a1.w;
        bf16x8 ah, al; split8(av, ah, al);
#pragma unroll
        for (int i = 0; i < NTW; ++i) {
            int n = (ntb + i) * 16 + nn;
            float wv[8];
#pragma unroll
            for (int j = 0; j < 8; ++j) {
                int k = kc * 32 + kg + j;
                float w = 0.f;
                if (KC * 32 <= KACT || k < KACT)
                    w = gW[(size_t)k * N + n];
                wv[j] = w;
            }
            bf16x8 bh, bl; split8(wv, bh, bl);
            aHH[i] = __builtin_amdgcn_mfma_f32_16x16x32_bf16(ah, bh, aHH[i], 0, 0, 0);
            aLH[i] = __builtin_amdgcn_mfma_f32_16x16x32_bf16(al, bh, aLH[i], 0, 0, 0);
            aHL[i] = __builtin_amdgcn_mfma_f32_16x16x32_bf16(ah, bl, aHL[i], 0, 0, 0);
        }
    }

    if (!SCATTER) __syncthreads();

#pragma unroll
    for (int i = 0; i < NTW; ++i) {
        int n = (ntb + i) * 16 + nn;
        float bv = bias[n];
#pragma unroll
        for (int r = 0; r < 4; ++r) {
            int m = mt * 16 + ((lane >> 4) << 2) + r;
            float h = ftanh(aHH[i][r] + aLH[i][r] + aHL[i][r] + bv);
            if (SCATTER) {
                unsafeAtomicAdd(out + (size_t)s_nodes[m] * 64 + n, h);
            } else {
                sO[m * SH + n] = h;
            }
        }
    }
}

__global__ __launch_bounds__(512) void edge_mlp_gather(
    const int* __restrict__ af_, const int* __restrict__ at_,
    const float* __restrict__ h_local, const float* __restrict__ h_global,
    const float* __restrict__ x_local, const float* __restrict__ x_global,
    const float* __restrict__ tsc,
    const float* __restrict__ fW0, const float* __restrict__ fb0,
    const float* __restrict__ fW1, const float* __restrict__ fb1,
    const float* __restrict__ fW2, const float* __restrict__ fb2,
    const float* __restrict__ tW0, const float* __restrict__ tb0,
    const float* __restrict__ tW1, const float* __restrict__ tb1,
    const float* __restrict__ tW2, const float* __restrict__ tb2,
    float* __restrict__ out)
{
    __shared__ float sA[TE * SA];
    __shared__ float sH[TE * SH];
    __shared__ int s_af[TE], s_at[TE];

    const int tid = threadIdx.x;
    const int e = tid >> 3, part = tid & 7;
    const int eg = blockIdx.x * TE + e;
    {
        int af = af_[eg], at = at_[eg];
        if (part == 0) { s_af[e] = af; s_at[e] = at; }
        int node = (part < 4) ? af : at;
        int k0 = ((part & 3) << 4) + ((part < 4) ? 0 : 64);
        const float4* hp = (const float4*)(h_local + (size_t)node * 64 + ((part & 3) << 4));
        float4* dst = (float4*)(sA + e * SA + k0);
        dst[0] = hp[0]; dst[1] = hp[1]; dst[2] = hp[2]; dst[3] = hp[3];
        if (part < 2) {
            int k0t = 128 + part * 16;
#pragma unroll
            for (int i = 0; i < 16; ++i) {
                int k = k0t + i;
                float x;
                if      (k < 132)  x = x_local[(size_t)eg * 4 + (k - 128)];
                else if (k < 148)  x = h_global[k - 132];
                else if (k < 152)  x = x_global[k - 148];
                else if (k == 152) x = tsc[0];
                else               x = 0.f;
                sA[e * SA + k] = x;
            }
        }
    }
    __syncthreads();
    layer<5,8,153,false>(sA, SA, fW0, fb0, sH, nullptr, nullptr, tid);
    __syncthreads();
    layer<4,8,128,false>(sH, SH, fW1, fb1, sH, nullptr, nullptr, tid);
    __syncthreads();
    layer<4,4,128,true >(sH, SH, fW2, fb2, nullptr, out, s_af, tid);
    __syncthreads();
    layer<5,8,153,false>(sA, SA, tW0, tb0, sH, nullptr, nullptr, tid);
    __syncthreads();
    layer<4,8,128,false>(sH, SH, tW1, tb1, sH, nullptr, nullptr, tid);
    __syncthreads();
    layer<4,4,128,true >(sH, SH, tW2, tb2, nullptr, out, s_at, tid);
}

__global__ __launch_bounds__(256) void tanh_kernel(float* __restrict__ out, int n4) {
    int i = blockIdx.x * blockDim.x + threadIdx.x;
    int stride = gridDim.x * blockDim.x;
    float4* p = (float4*)out;
    for (; i < n4; i += stride) {
        float4 v = p[i];
        v.x = ftanh(v.x); v.y = ftanh(v.y); v.z = ftanh(v.z); v.w = ftanh(v.w);
        p[i] = v;
    }
}

extern "C" void kernel_launch(void* const* d_in, const int* in_sizes, int n_in,
                              void* d_out, int out_size, void* d_ws, size_t ws_size,
                              hipStream_t stream) {
    const int*   addr_from = (const int*)d_in[0];
    const int*   addr_to   = (const int*)d_in[1];
    const float* h_local   = (const float*)d_in[2];
    const float* h_global  = (const float*)d_in[3];
    const float* x_local   = (const float*)d_in[4];
    const float* x_global  = (const float*)d_in[5];
    const float* tsc       = (const float*)d_in[6];
    const float* fW0 = (const float*)d_in[7];
    const float* fb0 = (const float*)d_in[8];
    const float* fW1 = (const float*)d_in[9];
    const float* fb1 = (const float*)d_in[10];
    const float* fW2 = (const float*)d_in[11];
    const float* fb2 = (const float*)d_in[12];
    const float* tW0 = (const float*)d_in[13];
    const float* tb0 = (const float*)d_in[14];
    const float* tW1 = (const float*)d_in[15];
    const float* tb1 = (const float*)d_in[16];
    const float* tW2 = (const float*)d_in[17];
    const float* tb2 = (const float*)d_in[18];
    float* out = (float*)d_out;

    hipMemsetAsync(d_out, 0, (size_t)NN * 64 * sizeof(float), stream);

    if (ws_size >= (size_t)WPK_BYTES) {
        ushort* wpk = (ushort*)d_ws;
        pack_w<<<WPK_TOTAL / 256, 256, 0, stream>>>(fW0, fW1, fW2, tW0, tW1, tW2, wpk);
        edge_mlp_packed<<<NE / TE, 512, 0, stream>>>(
            addr_from, addr_to, h_local, h_global, x_local, x_global, tsc,
            fb0, fb1, fb2, tb0, tb1, tb2, wpk, out);
    } else {
        edge_mlp_gather<<<NE / TE, 512, 0, stream>>>(
            addr_from, addr_to, h_local, h_global, x_local, x_global, tsc,
            fW0, fb0, fW1, fb1, fW2, fb2, tW0, tb0, tW1, tb1, tW2, tb2, out);
    }
    tanh_kernel<<<2048, 256, 0, stream>>>(out, NN * 64 / 4);
}